// Round 6
// baseline (211.632 us; speedup 1.0000x reference)
//
#include <hip/hip_runtime.h>
#include <cstdint>

// Problem constants
#define BATCH 2
#define TT    4
#define CKD   64      // key channels
#define CVD   256     // value channels
#define NQ    2048    // H*W (queries per batch)
#define MM    8192    // T*H*W (memory positions per batch)
#define TQ    64      // queries per block
#define TM    32      // memory rows per inner iteration
#define MSPLIT 16
#define MCHUNK (MM / MSPLIT)   // 512 = quarter of a T-slice
#define NIT    (MCHUNK / TM)   // 16

typedef unsigned short u16;
typedef __bf16 bf16x8 __attribute__((ext_vector_type(8)));
typedef float  f32x4  __attribute__((ext_vector_type(4)));

struct __attribute__((aligned(8)))  U16x4 { u16 x, y, z, w; };
struct __attribute__((aligned(16))) U16x8 { u16 v[8]; };

__device__ __forceinline__ u16 f2bf(float x) {
    uint32_t u = __float_as_uint(x);
    uint32_t r = (u + 0x7FFFu + ((u >> 16) & 1u)) >> 16;   // RNE
    return (u16)r;
}
__device__ __forceinline__ float bf2f(u16 h) {
    return __uint_as_float(((uint32_t)h) << 16);
}

#define MFMA(a, b, c) __builtin_amdgcn_mfma_f32_16x16x32_bf16((a), (b), (c), 0, 0, 0)

// Workspace layout (bytes) — total 47448064 (same footprint as R4)
#define WS_VB   0u           // 8 MB   bf16 V   [bt][c][m]
#define WS_KHI  8388608u     // 2 MB   bf16 Khi [bt][m][c]
#define WS_KLO  10485760u    // 2 MB   bf16 Klo [bt][m][c]
#define WS_QHI  12582912u    // 512 KB bf16 Qhi [b][n][c]
#define WS_QLO  13107200u    // 512 KB
#define WS_LP   13631488u    // 256 KB fp32 Lp[ms][b][n] (plain stores)
#define WS_UP   13893632u    // 32 MB  bf16 Up[ms][b][n][c] (plain stores)

// LDS (u16 units). K is NOT staged in LDS (QK A-fragments load straight from
// the pre-transposed [m][c] global layout — L2-resident, prefetched).
// Ps and V are double-buffered -> ONE barrier per iteration:
//   stage V(p) | prefetch V',K' | QK(K regs) -> Ps(p) | SYNC | PV(Ps(p),V(p))
// WAR on buffer p (rewrite at it+2) is separated by SYNC(it+1): a wave reaches
// it+2 staging only after SYNC(it+1), which implies all waves completed PV(it)
// (lgkmcnt drained at the barrier). Row pitch 40 u16 = 80 B = 16B-aligned
// (R5 lesson: pitch must be ≡0 mod 16 B for the b128 path).
#define LDS_PS  0         // 2 x (64 x 40)
#define LDS_PSZ 2560
#define LDS_VS  5120      // 2 x (256 x 40)
#define LDS_VSZ 10240
#define LDS_TOT 25600     // u16 -> 51200 B -> 3 blocks/CU

// ---------------------------------------------------------------------------
// prep_fused: block-range switch:
//   [0,4096)    pool_qv: 2x2 avg-pool query_value -> out channels [0,256)
//   [4096,6144) prep_v : fp32 V -> bf16, same [bt][c][m] layout
//   [6144,6656) prep_kq(mk): fp32 [g][64][2048] -> bf16 hi/lo transposed
//   [6656,6784) prep_kq(qk): same for query_key_low
// ---------------------------------------------------------------------------
__global__ __launch_bounds__(256)
void prep_fused(const float* __restrict__ qv, const float* __restrict__ mk,
                const float* __restrict__ qk, const float* __restrict__ mv,
                float* __restrict__ out, u16* __restrict__ vb,
                u16* __restrict__ khi, u16* __restrict__ klo,
                u16* __restrict__ qhi, u16* __restrict__ qlo) {
    const int bid = blockIdx.x;
    const int tid = threadIdx.x;

    if (bid < 4096) {
        // ---- pool_qv ----
        int idx = bid * 256 + tid;
        int n  = idx & 2047;
        int bc = idx >> 11;
        int x = n & 63, y = n >> 6;
        const float* ib = qv + (size_t)bc * (64 * 128) + (2 * y) * 128 + 2 * x;
        float2 r0 = *(const float2*)ib;
        float2 r1 = *(const float2*)(ib + 128);
        int b = bc >> 8, c = bc & 255;
        out[((size_t)(b * 512 + c)) * NQ + n] = 0.25f * (r0.x + r0.y + r1.x + r1.y);
    } else if (bid < 6144) {
        // ---- prep_v ----
        int idx = (bid - 4096) * 256 + tid;        // 0 .. 524287
        const float4* s = (const float4*)mv + (size_t)idx * 2;
        float4 a = s[0], b = s[1];
        U16x8 o;
        o.v[0] = f2bf(a.x); o.v[1] = f2bf(a.y); o.v[2] = f2bf(a.z); o.v[3] = f2bf(a.w);
        o.v[4] = f2bf(b.x); o.v[5] = f2bf(b.y); o.v[6] = f2bf(b.z); o.v[7] = f2bf(b.w);
        *(U16x8*)(vb + (size_t)idx * 8) = o;
    } else {
        // ---- prep_kq (mk: 512 blocks, qk: 128 blocks) ----
        const float* src;
        u16 *dhi, *dlo;
        int blk;
        if (bid < 6656) { src = mk; dhi = khi; dlo = klo; blk = bid - 6144; }
        else            { src = qk; dhi = qhi; dlo = qlo; blk = bid - 6656; }
        int g  = blk >> 6;
        int mg = blk & 63;
        int c8 = (tid & 7) * 8;
        int m  = mg * 32 + (tid >> 3);
        const float* s = src + (size_t)g * 64 * 2048 + m;
        U16x8 hi, lo;
        #pragma unroll
        for (int j = 0; j < 8; ++j) {
            float v = s[(size_t)(c8 + j) * 2048];
            u16 h = f2bf(v);
            hi.v[j] = h;
            lo.v[j] = f2bf(v - bf2f(h));
        }
        size_t o = ((size_t)g * 2048 + m) * 64 + c8;
        *(U16x8*)(dhi + o) = hi;
        *(U16x8*)(dlo + o) = lo;
    }
}

// ---------------------------------------------------------------------------
// flash_attn: U=sum(exp(S)*V) partials -> Up (bf16 plain stores, [n][c]),
// L partials -> Lp[ms][b][n] (plain stores after intra-block LDS combine).
// Grid: 1024 = b(2) x ntile(32) x mchunk(16). Block 256 = 4 waves.
// ---------------------------------------------------------------------------
__global__ __launch_bounds__(256, 3)
void flash_attn(const u16* __restrict__ khi_g, const u16* __restrict__ klo_g,
                const u16* __restrict__ vb_g, const u16* __restrict__ qhi_g,
                const u16* __restrict__ qlo_g, u16* __restrict__ Up,
                float* __restrict__ Lp) {
    __shared__ __align__(16) u16 smem[LDS_TOT];

    const int tid    = threadIdx.x;
    const int bx     = blockIdx.x;
    const int mchunk = bx & 15;
    const int ntile  = (bx >> 4) & 31;
    const int b      = bx >> 9;

    const int lane = tid & 63;
    const int w    = tid >> 6;
    const int quad = lane >> 4;
    const int l15  = lane & 15;

    const int bt      = b * TT + (mchunk >> 2);
    const int hw_base = (mchunk & 3) * MCHUNK;

    // ---- Q fragments straight from pre-transposed global [b][n][c] ----
    bf16x8 qh[2][2], ql[2][2];          // [nsi][kstep]
    {
        const int nbase = ntile * TQ + (w >> 1) * 32;
        #pragma unroll
        for (int nsi = 0; nsi < 2; ++nsi) {
            size_t o = ((size_t)(b * NQ + nbase + nsi * 16 + l15)) * 64 + quad * 8;
            qh[nsi][0] = *(const bf16x8*)&qhi_g[o];
            qh[nsi][1] = *(const bf16x8*)&qhi_g[o + 32];
            ql[nsi][0] = *(const bf16x8*)&qlo_g[o];
            ql[nsi][1] = *(const bf16x8*)&qlo_g[o + 32];
        }
    }

    const u16* kh_base = khi_g + ((size_t)bt * 2048 + hw_base) * 64;
    const u16* kl_base = klo_g + ((size_t)bt * 2048 + hw_base) * 64;
    const u16* v_base  = vb_g + (size_t)bt * CVD * 2048 + hw_base;

    f32x4 O[2][8];
    #pragma unroll
    for (int i = 0; i < 2; ++i)
        #pragma unroll
        for (int j = 0; j < 8; ++j)
            O[i][j] = (f32x4){0.f, 0.f, 0.f, 0.f};
    float Lloc[2] = {0.f, 0.f};

    const int msub     = w & 1;
    const int nsubpair = w >> 1;
    const int npair    = w & 1;
    const int chalf    = w >> 1;

    // staging lane maps (V only)
    const int vc = tid >> 2;            // 0..63
    const int vm = (tid & 3) * 8;       // 0..24

    // K fragment address for this wave (row m = hw0 + msub*16 + l15)
    const size_t k_off = (size_t)(msub * 16 + l15) * 64 + quad * 8;

    // ---- prologue: prefetch iter 0 (V to regs, K to regs) ----
    bf16x8 v_r[4];
    #pragma unroll
    for (int p = 0; p < 4; ++p)
        v_r[p] = *(const bf16x8*)&v_base[(size_t)(vc + p * 64) * 2048 + vm];
    bf16x8 khc[2], klc[2];
    #pragma unroll
    for (int ks = 0; ks < 2; ++ks) {
        khc[ks] = *(const bf16x8*)&kh_base[k_off + ks * 32];
        klc[ks] = *(const bf16x8*)&kl_base[k_off + ks * 32];
    }

    #pragma unroll 2
    for (int it = 0; it < NIT; ++it) {
        u16* Ps = smem + LDS_PS + (it & 1) * LDS_PSZ;   // [64][40]
        u16* Vs = smem + LDS_VS + (it & 1) * LDS_VSZ;   // [256][40]

        // ---- stage V tile (consumes v_r; waits only on the V loads) ----
        #pragma unroll
        for (int p = 0; p < 4; ++p)
            *(bf16x8*)&Vs[(vc + p * 64) * 40 + vm] = v_r[p];

        // ---- prefetch next iteration (V first: consumed earlier next iter) ----
        bf16x8 khn[2], kln[2];
        const bool more = (it + 1 < NIT);
        if (more) {
            const size_t row64 = (size_t)(it + 1) * TM * 64;
            #pragma unroll
            for (int p = 0; p < 4; ++p)
                v_r[p] = *(const bf16x8*)&v_base[(size_t)(vc + p * 64) * 2048 + (it + 1) * TM + vm];
            #pragma unroll
            for (int ks = 0; ks < 2; ++ks) {
                khn[ks] = *(const bf16x8*)&kh_base[row64 + k_off + ks * 32];
                kln[ks] = *(const bf16x8*)&kl_base[row64 + k_off + ks * 32];
            }
        }

        // ---- QK from registers: S[msub*16..+16][nsubpair*32..+32] ----
        f32x4 acc[2];
        acc[0] = (f32x4){0.f, 0.f, 0.f, 0.f};
        acc[1] = (f32x4){0.f, 0.f, 0.f, 0.f};
        #pragma unroll
        for (int ks = 0; ks < 2; ++ks) {
            #pragma unroll
            for (int nsi = 0; nsi < 2; ++nsi) {
                acc[nsi] = MFMA(khc[ks], qh[nsi][ks], acc[nsi]);
                acc[nsi] = MFMA(khc[ks], ql[nsi][ks], acc[nsi]);
                acc[nsi] = MFMA(klc[ks], qh[nsi][ks], acc[nsi]);
            }
        }
        // ---- P = exp(S) -> Ps[n][m] (A-operand layout); accumulate L ----
        #pragma unroll
        for (int nsi = 0; nsi < 2; ++nsi) {
            int n = (nsubpair * 2 + nsi) * 16 + l15;
            float p0 = __expf(acc[nsi][0]);
            float p1 = __expf(acc[nsi][1]);
            float p2 = __expf(acc[nsi][2]);
            float p3 = __expf(acc[nsi][3]);
            Lloc[nsi] += (p0 + p1) + (p2 + p3);
            U16x4 pk = {f2bf(p0), f2bf(p1), f2bf(p2), f2bf(p3)};
            *(U16x4*)&Ps[n * 40 + msub * 16 + quad * 4] = pk;
        }
        __syncthreads();   // the ONE barrier: V(p), Ps(p) visible

        // ---- PV: wave owns O[npair*32..+32][chalf*128..+128] ----
        bf16x8 a2[2];
        #pragma unroll
        for (int nsi2 = 0; nsi2 < 2; ++nsi2)
            a2[nsi2] = *(const bf16x8*)&Ps[(npair * 32 + nsi2 * 16 + l15) * 40 + quad * 8];
        #pragma unroll
        for (int cs = 0; cs < 8; ++cs) {
            bf16x8 bv = *(const bf16x8*)&Vs[(chalf * 128 + cs * 16 + l15) * 40 + quad * 8];
            O[0][cs] = MFMA(a2[0], bv, O[0][cs]);
            O[1][cs] = MFMA(a2[1], bv, O[1][cs]);
        }

        // ---- rotate K prefetch ----
        if (more) {
            khc[0] = khn[0]; khc[1] = khn[1];
            klc[0] = kln[0]; klc[1] = kln[1];
        }
    }

    // ---- L: fold quads via shuffle, combine msub halves via LDS, store ----
    float* Larr = (float*)smem;   // 128 floats; Ps buf0 region, safe (see text)
    #pragma unroll
    for (int nsi = 0; nsi < 2; ++nsi) {
        float v = Lloc[nsi];
        v += __shfl_xor(v, 16);
        v += __shfl_xor(v, 32);
        if (quad == nsi)
            Larr[msub * 64 + (nsubpair * 2 + nsi) * 16 + l15] = v;
    }
    __syncthreads();
    if (tid < 64)
        Lp[((size_t)mchunk * BATCH + b) * NQ + ntile * TQ + tid] = Larr[tid] + Larr[64 + tid];

    // ---- U partials: bf16 plain stores, layout [ms][b][n][c] ----
    u16* ubase = Up + (((size_t)mchunk * BATCH + b) * NQ + ntile * TQ) * CVD
               + (size_t)(npair * 32) * CVD + chalf * 128;
    #pragma unroll
    for (int nsi2 = 0; nsi2 < 2; ++nsi2) {
        #pragma unroll
        for (int cs = 0; cs < 8; ++cs) {
            #pragma unroll
            for (int r = 0; r < 4; ++r) {
                int n_local = nsi2 * 16 + quad * 4 + r;
                ubase[(size_t)n_local * CVD + cs * 16 + l15] = f2bf(O[nsi2][cs][r]);
            }
        }
    }
}

// ---------------------------------------------------------------------------
// reduce_div: out[b,256+c,n] = (sum_ms Up[ms][b][n][c]) / (sum_ms Lp[ms][b][n])
// Grid: 1024 = b(2) x nslab(128, 16 n each) x cquarter(4, 64 c each).
// ---------------------------------------------------------------------------
__global__ __launch_bounds__(256) void reduce_div(const u16* __restrict__ Up,
                                                  const float* __restrict__ Lp,
                                                  float* __restrict__ out) {
    __shared__ float lds[16 * 65];
    const int tid = threadIdx.x;
    const int cq  = blockIdx.x & 3;
    const int n0  = ((blockIdx.x >> 2) & 127) * 16;
    const int b   = blockIdx.x >> 9;

    const int n_local = tid >> 4;          // 0..15
    const int c_loc   = (tid & 15) * 4;    // 0..60
    const int c       = cq * 64 + c_loc;

    float a0 = 0.f, a1 = 0.f, a2 = 0.f, a3 = 0.f;
    for (int ms = 0; ms < MSPLIT; ++ms) {
        U16x4 v = *(const U16x4*)(Up + (((size_t)ms * BATCH + b) * NQ + n0 + n_local) * CVD + c);
        a0 += bf2f(v.x); a1 += bf2f(v.y); a2 += bf2f(v.z); a3 += bf2f(v.w);
    }

    float Lsum = 0.f;
    #pragma unroll
    for (int ms = 0; ms < MSPLIT; ++ms)
        Lsum += Lp[((size_t)ms * BATCH + b) * NQ + n0 + n_local];
    const float inv = 1.0f / Lsum;

    lds[n_local * 65 + c_loc + 0] = a0 * inv;
    lds[n_local * 65 + c_loc + 1] = a1 * inv;
    lds[n_local * 65 + c_loc + 2] = a2 * inv;
    lds[n_local * 65 + c_loc + 3] = a3 * inv;
    __syncthreads();

    // transpose write: out[b][256+cq*64+c_out][n0 + nq .. +4)
    const int c_out = tid >> 2;            // 0..63
    const int nq    = (tid & 3) * 4;       // 0..12
    float4 v;
    v.x = lds[(nq + 0) * 65 + c_out];
    v.y = lds[(nq + 1) * 65 + c_out];
    v.z = lds[(nq + 2) * 65 + c_out];
    v.w = lds[(nq + 3) * 65 + c_out];
    *(float4*)(out + ((size_t)(b * 512 + 256 + cq * 64 + c_out)) * NQ + n0 + nq) = v;
}

extern "C" void kernel_launch(void* const* d_in, const int* in_sizes, int n_in,
                              void* d_out, int out_size, void* d_ws, size_t ws_size,
                              hipStream_t stream) {
    const float* qv = (const float*)d_in[0];   // query_value       [2,256,64,128]
    const float* mk = (const float*)d_in[1];   // memory_keys_low   [2,4,64,32,64]
    const float* mv = (const float*)d_in[2];   // memory_values_low [2,4,256,32,64]
    const float* qk = (const float*)d_in[3];   // query_key_low     [2,64,32,64]
    float* out = (float*)d_out;                // [2,512,32,64] fp32

    u16*   vb  = (u16*)((char*)d_ws + WS_VB);
    u16*   khi = (u16*)((char*)d_ws + WS_KHI);
    u16*   klo = (u16*)((char*)d_ws + WS_KLO);
    u16*   qhi = (u16*)((char*)d_ws + WS_QHI);
    u16*   qlo = (u16*)((char*)d_ws + WS_QLO);
    float* Lp  = (float*)((char*)d_ws + WS_LP);
    u16*   Up  = (u16*)((char*)d_ws + WS_UP);

    prep_fused<<<6784, 256, 0, stream>>>(qv, mk, qk, mv, out, vb, khi, klo, qhi, qlo);
    flash_attn<<<1024, 256, 0, stream>>>(khi, klo, vb, qhi, qlo, Up, Lp);
    reduce_div<<<1024, 256, 0, stream>>>(Up, Lp, out);
}

// Round 7
// 133.571 us; speedup vs baseline: 1.5844x; 1.5844x over previous
//
#include <hip/hip_runtime.h>
#include <cstdint>

// Problem constants
#define BATCH 2
#define TT    4
#define CKD   64      // key channels
#define CVD   256     // value channels
#define NQ    2048    // H*W (queries per batch)
#define MM    8192    // T*H*W (memory positions per batch)
#define TQ    64      // queries per block
#define TM    32      // memory rows per inner iteration
#define MSPLIT 8
#define MCHUNK (MM / MSPLIT)   // 1024 = half a T-slice
#define NIT    (MCHUNK / TM)   // 32

typedef unsigned short u16;
typedef __bf16 bf16x8 __attribute__((ext_vector_type(8)));
typedef float  f32x4  __attribute__((ext_vector_type(4)));

struct __attribute__((aligned(8)))  U16x4 { u16 x, y, z, w; };
struct __attribute__((aligned(16))) U16x8 { u16 v[8]; };

__device__ __forceinline__ u16 f2bf(float x) {
    uint32_t u = __float_as_uint(x);
    uint32_t r = (u + 0x7FFFu + ((u >> 16) & 1u)) >> 16;   // RNE
    return (u16)r;
}
__device__ __forceinline__ float bf2f(u16 h) {
    return __uint_as_float(((uint32_t)h) << 16);
}

#define MFMA(a, b, c) __builtin_amdgcn_mfma_f32_16x16x32_bf16((a), (b), (c), 0, 0, 0)

// Workspace layout (bytes) — R4 layout (fp32 Up: bf16 partials were a wash on
// bytes at MSPLIT=16 and halved write efficiency — R6 lesson)
#define WS_VB   0u           // 8 MB   bf16 V   [bt][c][m]
#define WS_KHI  8388608u     // 2 MB   bf16 Khi [bt][m][c]
#define WS_KLO  10485760u    // 2 MB   bf16 Klo [bt][m][c]
#define WS_QHI  12582912u    // 512 KB bf16 Qhi [b][n][c]
#define WS_QLO  13107200u    // 512 KB
#define WS_LP   13631488u    // 256 KB fp32 Lp[ms][msub][b][n] (plain stores)
#define WS_UP   13893632u    // 32 MB  fp32 Up[ms][b][n][c]   (plain stores)

// ---------------------------------------------------------------------------
// prep_fused: block-range switch:
//   [0,4096)    pool_qv: 2x2 avg-pool query_value -> out channels [0,256)
//   [4096,6144) prep_v : fp32 V -> bf16, same [bt][c][m] layout
//   [6144,6400) prep_kq(mk): coalesced read + LDS transpose -> bf16 hi/lo [m][c]
//   [6400,6464) prep_kq(qk): same for query_key_low
// ---------------------------------------------------------------------------
__global__ __launch_bounds__(256)
void prep_fused(const float* __restrict__ qv, const float* __restrict__ mk,
                const float* __restrict__ qk, const float* __restrict__ mv,
                float* __restrict__ out, u16* __restrict__ vb,
                u16* __restrict__ khi, u16* __restrict__ klo,
                u16* __restrict__ qhi, u16* __restrict__ qlo) {
    __shared__ float tile[64 * 65];   // kq branch only (block-uniform branches)
    const int bid = blockIdx.x;
    const int tid = threadIdx.x;

    if (bid < 4096) {
        // ---- pool_qv ----
        int idx = bid * 256 + tid;
        int n  = idx & 2047;
        int bc = idx >> 11;
        int x = n & 63, y = n >> 6;
        const float* ib = qv + (size_t)bc * (64 * 128) + (2 * y) * 128 + 2 * x;
        float2 r0 = *(const float2*)ib;
        float2 r1 = *(const float2*)(ib + 128);
        int b = bc >> 8, c = bc & 255;
        out[((size_t)(b * 512 + c)) * NQ + n] = 0.25f * (r0.x + r0.y + r1.x + r1.y);
    } else if (bid < 6144) {
        // ---- prep_v ----
        int idx = (bid - 4096) * 256 + tid;        // 0 .. 524287
        const float4* s = (const float4*)mv + (size_t)idx * 2;
        float4 a = s[0], b = s[1];
        U16x8 o;
        o.v[0] = f2bf(a.x); o.v[1] = f2bf(a.y); o.v[2] = f2bf(a.z); o.v[3] = f2bf(a.w);
        o.v[4] = f2bf(b.x); o.v[5] = f2bf(b.y); o.v[6] = f2bf(b.z); o.v[7] = f2bf(b.w);
        *(U16x8*)(vb + (size_t)idx * 8) = o;
    } else {
        // ---- prep_kq: per block one 64c x 64m tile, transposed via LDS ----
        const float* src;
        u16 *dhi, *dlo;
        int blk;
        if (bid < 6400) { src = mk; dhi = khi; dlo = klo; blk = bid - 6144; }
        else            { src = qk; dhi = qhi; dlo = qlo; blk = bid - 6400; }
        const int g  = blk >> 5;           // mk: 0..7, qk: 0..1
        const int mg = blk & 31;           // 64-m tile index
        const float* s = src + (size_t)g * 64 * 2048 + mg * 64;

        // coalesced read: c = tid>>2, q = tid&3; 4 float4 per thread
        const int c = tid >> 2;
        const int q = tid & 3;
        #pragma unroll
        for (int i = 0; i < 4; ++i) {
            float4 v = *(const float4*)(s + (size_t)c * 2048 + q * 16 + i * 4);
            int m = q * 16 + i * 4;
            tile[(m + 0) * 65 + c] = v.x;
            tile[(m + 1) * 65 + c] = v.y;
            tile[(m + 2) * 65 + c] = v.z;
            tile[(m + 3) * 65 + c] = v.w;
        }
        __syncthreads();

        // coalesced write: mo = tid>>2, cb = (tid&3)*16; hi/lo split here
        const int mo = tid >> 2;
        const int cb = (tid & 3) * 16;
        U16x8 h0, h1, l0, l1;
        #pragma unroll
        for (int j = 0; j < 8; ++j) {
            float v = tile[mo * 65 + cb + j];
            u16 h = f2bf(v);
            h0.v[j] = h; l0.v[j] = f2bf(v - bf2f(h));
            float v2 = tile[mo * 65 + cb + 8 + j];
            u16 h2 = f2bf(v2);
            h1.v[j] = h2; l1.v[j] = f2bf(v2 - bf2f(h2));
        }
        size_t o = ((size_t)g * 2048 + mg * 64 + mo) * 64 + cb;
        *(U16x8*)(dhi + o) = h0; *(U16x8*)(dhi + o + 8) = h1;
        *(U16x8*)(dlo + o) = l0; *(U16x8*)(dlo + o + 8) = l1;
    }
}

// ---------------------------------------------------------------------------
// flash_attn: R4 structure (known 49.8 us) with ONE change: the global
// prefetch for iteration it+1 is issued after sync2 instead of right before
// sync1, so the vmcnt(0) drain at sync1(it+1) happens ~300 cyc (PV span +
// staging) after issue instead of ~50 cyc — L2 latency covered.
// Double-buffered LDS (K/V/Ps x2): 2 barriers per iteration.
// Grid: 512 = b(2) x ntile(32) x mchunk(8). Block 256 = 4 waves.
// ---------------------------------------------------------------------------
__global__ __launch_bounds__(256, 2)
void flash_attn(const u16* __restrict__ khi_g, const u16* __restrict__ klo_g,
                const u16* __restrict__ vb_g, const u16* __restrict__ qhi_g,
                const u16* __restrict__ qlo_g, float* __restrict__ Up,
                float* __restrict__ Lp) {
    // Per buffer (u16 units): Khi[32][72] | Klo[32][72] | Vs[256][40] | Ps[64][40]
    // Row pitches 72/40 u16 = 144/80 B, both 16B-aligned (R5 lesson).
    __shared__ __align__(16) u16 smem[2][17408];

    const int tid    = threadIdx.x;
    const int bx     = blockIdx.x;
    const int mchunk = bx & 7;
    const int ntile  = (bx >> 3) & 31;
    const int b      = bx >> 8;

    const int lane = tid & 63;
    const int w    = tid >> 6;
    const int quad = lane >> 4;
    const int l15  = lane & 15;

    const int bt      = b * TT + (mchunk >> 1);
    const int hw_base = (mchunk & 1) * MCHUNK;

    // ---- Q fragments straight from pre-transposed global [b][n][c] ----
    bf16x8 qh[2][2], ql[2][2];          // [nsi][kstep]
    {
        const int nbase = ntile * TQ + (w >> 1) * 32;
        #pragma unroll
        for (int nsi = 0; nsi < 2; ++nsi) {
            size_t o = ((size_t)(b * NQ + nbase + nsi * 16 + l15)) * 64 + quad * 8;
            qh[nsi][0] = *(const bf16x8*)&qhi_g[o];
            qh[nsi][1] = *(const bf16x8*)&qhi_g[o + 32];
            ql[nsi][0] = *(const bf16x8*)&qlo_g[o];
            ql[nsi][1] = *(const bf16x8*)&qlo_g[o + 32];
        }
    }

    const u16* kh_base = khi_g + ((size_t)bt * 2048 + hw_base) * 64;
    const u16* kl_base = klo_g + ((size_t)bt * 2048 + hw_base) * 64;
    const u16* v_base  = vb_g + (size_t)bt * CVD * 2048 + hw_base;

    f32x4 O[2][8];
    #pragma unroll
    for (int i = 0; i < 2; ++i)
        #pragma unroll
        for (int j = 0; j < 8; ++j)
            O[i][j] = (f32x4){0.f, 0.f, 0.f, 0.f};
    float Lloc[2] = {0.f, 0.f};

    const int msub     = w & 1;
    const int nsubpair = w >> 1;
    const int npair    = w & 1;
    const int chalf    = w >> 1;

    // staging lane maps
    const int km = tid >> 3;            // 0..31
    const int kc = (tid & 7) * 8;       // 0..56
    const int vc = tid >> 2;            // 0..63
    const int vm = (tid & 3) * 8;       // 0..24

    // ---- prologue: prefetch iter 0 into registers ----
    bf16x8 kh_r = *(const bf16x8*)&kh_base[(size_t)km * 64 + kc];
    bf16x8 kl_r = *(const bf16x8*)&kl_base[(size_t)km * 64 + kc];
    bf16x8 v_r[4];
    #pragma unroll
    for (int p = 0; p < 4; ++p)
        v_r[p] = *(const bf16x8*)&v_base[(size_t)(vc + p * 64) * 2048 + vm];

    #pragma unroll 2
    for (int it = 0; it < NIT; ++it) {
        u16* Khi = smem[it & 1];
        u16* Klo = Khi + 2304;
        u16* Vs  = Khi + 4608;
        u16* Ps  = Khi + 14848;

        // ---- stage prefetched tile into this iteration's buffer ----
        *(bf16x8*)&Khi[km * 72 + kc] = kh_r;
        *(bf16x8*)&Klo[km * 72 + kc] = kl_r;
        #pragma unroll
        for (int p = 0; p < 4; ++p)
            *(bf16x8*)&Vs[(vc + p * 64) * 40 + vm] = v_r[p];
        __syncthreads();   // sync1: staging visible (drains any pending vmem)

        // ---- QK: S[msub*16..+16][nsubpair*32..+32], 3-term hi/lo split ----
        f32x4 acc[2];
        acc[0] = (f32x4){0.f, 0.f, 0.f, 0.f};
        acc[1] = (f32x4){0.f, 0.f, 0.f, 0.f};
        #pragma unroll
        for (int ks = 0; ks < 2; ++ks) {
            bf16x8 ah = *(const bf16x8*)&Khi[(msub * 16 + l15) * 72 + ks * 32 + quad * 8];
            bf16x8 al = *(const bf16x8*)&Klo[(msub * 16 + l15) * 72 + ks * 32 + quad * 8];
            #pragma unroll
            for (int nsi = 0; nsi < 2; ++nsi) {
                acc[nsi] = MFMA(ah, qh[nsi][ks], acc[nsi]);
                acc[nsi] = MFMA(ah, ql[nsi][ks], acc[nsi]);
                acc[nsi] = MFMA(al, qh[nsi][ks], acc[nsi]);
            }
        }
        // ---- P = exp(S) -> Ps[n][m] (A-operand layout); accumulate L ----
        #pragma unroll
        for (int nsi = 0; nsi < 2; ++nsi) {
            int n = (nsubpair * 2 + nsi) * 16 + l15;
            float p0 = __expf(acc[nsi][0]);
            float p1 = __expf(acc[nsi][1]);
            float p2 = __expf(acc[nsi][2]);
            float p3 = __expf(acc[nsi][3]);
            Lloc[nsi] += (p0 + p1) + (p2 + p3);
            U16x4 pk = {f2bf(p0), f2bf(p1), f2bf(p2), f2bf(p3)};
            *(U16x4*)&Ps[n * 40 + msub * 16 + quad * 4] = pk;
        }
        __syncthreads();   // sync2: Ps visible

        // ---- prefetch it+1 HERE: drains at sync1(it+1), covered by PV ----
        if (it + 1 < NIT) {
            const int hw1 = (it + 1) * TM;
            kh_r = *(const bf16x8*)&kh_base[(size_t)(hw1 + km) * 64 + kc];
            kl_r = *(const bf16x8*)&kl_base[(size_t)(hw1 + km) * 64 + kc];
            #pragma unroll
            for (int p = 0; p < 4; ++p)
                v_r[p] = *(const bf16x8*)&v_base[(size_t)(vc + p * 64) * 2048 + hw1 + vm];
        }

        // ---- PV: wave owns O[npair*32..+32][chalf*128..+128] ----
        bf16x8 a2[2];
        #pragma unroll
        for (int nsi2 = 0; nsi2 < 2; ++nsi2)
            a2[nsi2] = *(const bf16x8*)&Ps[(npair * 32 + nsi2 * 16 + l15) * 40 + quad * 8];
        #pragma unroll
        for (int cs = 0; cs < 8; ++cs) {
            bf16x8 bv = *(const bf16x8*)&Vs[(chalf * 128 + cs * 16 + l15) * 40 + quad * 8];
            O[0][cs] = MFMA(a2[0], bv, O[0][cs]);
            O[1][cs] = MFMA(a2[1], bv, O[1][cs]);
        }
        // no barrier: next staging writes the other buffer
    }

    // ---- L partials: fold quads via shuffle, plain store (disjoint slices) ----
    #pragma unroll
    for (int nsi = 0; nsi < 2; ++nsi) {
        float v = Lloc[nsi];
        v += __shfl_xor(v, 16);
        v += __shfl_xor(v, 32);
        if (quad == nsi) {
            int nsub = nsubpair * 2 + nsi;
            Lp[(((size_t)mchunk * 2 + msub) * BATCH + b) * NQ + ntile * TQ + nsub * 16 + l15] = v;
        }
    }

    // ---- U partials: plain coalesced fp32 stores, layout [ms][b][n][c] ----
    float* ubase = Up + (((size_t)mchunk * BATCH + b) * NQ + ntile * TQ) * CVD
                 + (size_t)(npair * 32) * CVD + chalf * 128;
    #pragma unroll
    for (int nsi2 = 0; nsi2 < 2; ++nsi2) {
        #pragma unroll
        for (int cs = 0; cs < 8; ++cs) {
            #pragma unroll
            for (int r = 0; r < 4; ++r) {
                int n_local = nsi2 * 16 + quad * 4 + r;
                ubase[(size_t)n_local * CVD + cs * 16 + l15] = O[nsi2][cs][r];
            }
        }
    }
}

// ---------------------------------------------------------------------------
// reduce_div: out[b,256+c,n] = (sum_ms Up[ms][b][n][c]) / (sum_s Lp[s][b][n])
// Grid: 1024 = b(2) x nslab(128, 16 n each) x cquarter(4, 64 c each).
// ---------------------------------------------------------------------------
__global__ __launch_bounds__(256) void reduce_div(const float* __restrict__ Up,
                                                  const float* __restrict__ Lp,
                                                  float* __restrict__ out) {
    __shared__ float lds[16 * 65];
    const int tid = threadIdx.x;
    const int cq  = blockIdx.x & 3;
    const int n0  = ((blockIdx.x >> 2) & 127) * 16;
    const int b   = blockIdx.x >> 9;

    const int n_local = tid >> 4;          // 0..15
    const int c_loc   = (tid & 15) * 4;    // 0..60
    const int c       = cq * 64 + c_loc;

    float4 acc = {0.f, 0.f, 0.f, 0.f};
    for (int ms = 0; ms < MSPLIT; ++ms) {
        float4 v = *(const float4*)(Up + (((size_t)ms * BATCH + b) * NQ + n0 + n_local) * CVD + c);
        acc.x += v.x; acc.y += v.y; acc.z += v.z; acc.w += v.w;
    }

    float Lsum = 0.f;
    #pragma unroll
    for (int s = 0; s < MSPLIT * 2; ++s)
        Lsum += Lp[((size_t)s * BATCH + b) * NQ + n0 + n_local];
    const float inv = 1.0f / Lsum;

    lds[n_local * 65 + c_loc + 0] = acc.x * inv;
    lds[n_local * 65 + c_loc + 1] = acc.y * inv;
    lds[n_local * 65 + c_loc + 2] = acc.z * inv;
    lds[n_local * 65 + c_loc + 3] = acc.w * inv;
    __syncthreads();

    // transpose write: out[b][256+cq*64+c_out][n0 + nq .. +4)
    const int c_out = tid >> 2;            // 0..63
    const int nq    = (tid & 3) * 4;       // 0..12
    float4 v;
    v.x = lds[(nq + 0) * 65 + c_out];
    v.y = lds[(nq + 1) * 65 + c_out];
    v.z = lds[(nq + 2) * 65 + c_out];
    v.w = lds[(nq + 3) * 65 + c_out];
    *(float4*)(out + ((size_t)(b * 512 + 256 + cq * 64 + c_out)) * NQ + n0 + nq) = v;
}

extern "C" void kernel_launch(void* const* d_in, const int* in_sizes, int n_in,
                              void* d_out, int out_size, void* d_ws, size_t ws_size,
                              hipStream_t stream) {
    const float* qv = (const float*)d_in[0];   // query_value       [2,256,64,128]
    const float* mk = (const float*)d_in[1];   // memory_keys_low   [2,4,64,32,64]
    const float* mv = (const float*)d_in[2];   // memory_values_low [2,4,256,32,64]
    const float* qk = (const float*)d_in[3];   // query_key_low     [2,64,32,64]
    float* out = (float*)d_out;                // [2,512,32,64] fp32

    u16*   vb  = (u16*)((char*)d_ws + WS_VB);
    u16*   khi = (u16*)((char*)d_ws + WS_KHI);
    u16*   klo = (u16*)((char*)d_ws + WS_KLO);
    u16*   qhi = (u16*)((char*)d_ws + WS_QHI);
    u16*   qlo = (u16*)((char*)d_ws + WS_QLO);
    float* Lp  = (float*)((char*)d_ws + WS_LP);
    float* Up  = (float*)((char*)d_ws + WS_UP);

    prep_fused<<<6464, 256, 0, stream>>>(qv, mk, qk, mv, out, vb, khi, klo, qhi, qlo);
    flash_attn<<<512, 256, 0, stream>>>(khi, klo, vb, qhi, qlo, Up, Lp);
    reduce_div<<<1024, 256, 0, stream>>>(Up, Lp, out);
}